// Round 6
// baseline (237.336 us; speedup 1.0000x reference)
//
#include <hip/hip_runtime.h>
#include <math.h>

// Problem constants
#define NPIX   131072      // B*H*W = 32*64*64
#define KEMB   512
#define DDIM   64
#define HW     4096        // H*W
#define BSTRIDE 262144     // C*H*W

// d_out flat layout (float32): [loss(1) | out(8388608) | perplexity(1) | indices(131072)]
#define OUT_OFF  1
#define PERP_OFF 8388609
#define IDX_OFF  8388610

typedef __attribute__((ext_vector_type(8))) short bf16x8;   // 8 bf16 = 4 VGPRs (MFMA A/B frag)
typedef __attribute__((ext_vector_type(4))) float f32x4;    // MFMA C/D frag

__device__ __forceinline__ unsigned short bf16_rtne(float f) {
    unsigned int u = __float_as_uint(f);
    u += 0x7FFFu + ((u >> 16) & 1u);
    return (unsigned short)(u >> 16);
}
__device__ __forceinline__ float bf16_to_f(unsigned short h) {
    return __uint_as_float(((unsigned int)h) << 16);
}

// 6 split-products per k-step: hh, hm, mh, hl, lh, mm
#define MFMA_STEP(AH, AM, AL, XH, XM, XL, ACC) \
    ACC = __builtin_amdgcn_mfma_f32_16x16x32_bf16(AH, XH, ACC, 0, 0, 0); \
    ACC = __builtin_amdgcn_mfma_f32_16x16x32_bf16(AH, XM, ACC, 0, 0, 0); \
    ACC = __builtin_amdgcn_mfma_f32_16x16x32_bf16(AM, XH, ACC, 0, 0, 0); \
    ACC = __builtin_amdgcn_mfma_f32_16x16x32_bf16(AH, XL, ACC, 0, 0, 0); \
    ACC = __builtin_amdgcn_mfma_f32_16x16x32_bf16(AL, XH, ACC, 0, 0, 0); \
    ACC = __builtin_amdgcn_mfma_f32_16x16x32_bf16(AM, XM, ACC, 0, 0, 0);

// ws layout: [0,2048) int counts | [2048,4096) float hnorms | [4096] loss |
//            [8192) ebh ushort[32768] | +64KB ebm | +64KB ebl
// 512 blocks x 64 threads: block = code, lane = channel.
__global__ void vq_init(const float* __restrict__ emb, int* __restrict__ counts,
                        float* __restrict__ hnorms, float* __restrict__ loss_acc,
                        unsigned short* __restrict__ ebh, unsigned short* __restrict__ ebm,
                        unsigned short* __restrict__ ebl) {
    const int k = blockIdx.x;
    const int c = threadIdx.x;
    float x = emb[k * DDIM + c];
    unsigned short h = bf16_rtne(x);
    float r1 = x - bf16_to_f(h);          // exact (Sterbenz)
    unsigned short m = bf16_rtne(r1);
    float r2 = r1 - bf16_to_f(m);         // exact
    unsigned short l = bf16_rtne(r2);
    ebh[k * DDIM + c] = h; ebm[k * DDIM + c] = m; ebl[k * DDIM + c] = l;
    float s = x * x;
#pragma unroll
    for (int off = 1; off <= 32; off <<= 1) s += __shfl_xor(s, off, 64);
    if (c == 0) {
        hnorms[k] = 0.5f * s;
        counts[k] = 0;
        if (k == 0) *loss_acc = 0.f;
    }
}

// Wave owns 32 pixels (2 B-tiles of N=16); 1024 blocks -> 4 blocks/CU for TLP.
// Codes stream as A-tiles (M=16) with manual double-buffer (static reg names —
// runtime-indexed arrays go to scratch, R4: 429 MB spill traffic).
// Approx score = 0.5||e||^2 - x.e via triple-bf16 MFMA -> top-2 candidates,
// then exact fp32 rescore of the 2 candidates (matches np's fp32 decisions).
__global__ __launch_bounds__(256, 3) void vq_main(
    const float* __restrict__ in, const float* __restrict__ emb,
    const unsigned short* __restrict__ ebh, const unsigned short* __restrict__ ebm,
    const unsigned short* __restrict__ ebl,
    const float* __restrict__ hnorms, int* __restrict__ counts,
    float* __restrict__ loss_acc, float* __restrict__ dout)
{
    __shared__ int hist[KEMB];
    const int t = threadIdx.x;
    hist[t] = 0; hist[t + 256] = 0;
    __syncthreads();

    const int lane = t & 63;
    const int wid  = t >> 6;
    const int quad = lane >> 4;
    const int col  = lane & 15;
    const int b    = blockIdx.x >> 5;                         // 32 blocks per image
    const int p0   = ((blockIdx.x & 31) << 7) | (wid << 5);   // first of 32 pixels
    const float* xb = in + b * BSTRIDE;

    // ---- Build x B-fragments: B[n=col][k=quad*8+j], xf[split][ptile][kstep] ----
    bf16x8 xf[3][2][2];
#pragma unroll
    for (int tt = 0; tt < 2; ++tt) {
#pragma unroll
        for (int s = 0; s < 2; ++s) {
            const int pp = p0 + tt * 16 + col;
            const int c0 = s * 32 + quad * 8;
            bf16x8 vh, vm, vl;
#pragma unroll
            for (int j = 0; j < 8; ++j) {
                float x = xb[(c0 + j) * HW + pp];
                unsigned short h = bf16_rtne(x);
                float r1 = x - bf16_to_f(h);
                unsigned short m = bf16_rtne(r1);
                float r2 = r1 - bf16_to_f(m);
                unsigned short l = bf16_rtne(r2);
                vh[j] = (short)h; vm[j] = (short)m; vl[j] = (short)l;
            }
            xf[0][tt][s] = vh; xf[1][tt][s] = vm; xf[2][tt][s] = vl;
        }
    }

    const int arow = col * DDIM + quad * 8;   // lane offset within a code-tile (ushorts)

    // top-2 tracking per pixel-tile (lex order on (value, index))
    float v1[2], v2[2]; int k1[2], k2[2];
#pragma unroll
    for (int tt = 0; tt < 2; ++tt) {
        v1[tt] = 3.402823466e38f; v2[tt] = 3.402823466e38f; k1[tt] = 0; k2[tt] = 0;
    }

    // Preload tile 0 (A buffer) + its norms
    bf16x8 Ah0 = *(const bf16x8*)(ebh + arow);
    bf16x8 Ah1 = *(const bf16x8*)(ebh + arow + 32);
    bf16x8 Am0 = *(const bf16x8*)(ebm + arow);
    bf16x8 Am1 = *(const bf16x8*)(ebm + arow + 32);
    bf16x8 Al0 = *(const bf16x8*)(ebl + arow);
    bf16x8 Al1 = *(const bf16x8*)(ebl + arow + 32);
    f32x4 hnA = *(const f32x4*)(hnorms + quad * 4);

    for (int ct = 0; ct < 32; ct += 2) {
        // ---- prefetch tile ct+1 (B buffer) while computing tile ct ----
        const int offB = (ct + 1) * (16 * DDIM) + arow;
        const bf16x8 Bh0 = *(const bf16x8*)(ebh + offB);
        const bf16x8 Bh1 = *(const bf16x8*)(ebh + offB + 32);
        const bf16x8 Bm0 = *(const bf16x8*)(ebm + offB);
        const bf16x8 Bm1 = *(const bf16x8*)(ebm + offB + 32);
        const bf16x8 Bl0 = *(const bf16x8*)(ebl + offB);
        const bf16x8 Bl1 = *(const bf16x8*)(ebl + offB + 32);
        const f32x4 hnB = *(const f32x4*)(hnorms + (ct + 1) * 16 + quad * 4);

        f32x4 acc0 = (f32x4){0.f, 0.f, 0.f, 0.f};
        f32x4 acc1 = (f32x4){0.f, 0.f, 0.f, 0.f};
        MFMA_STEP(Ah0, Am0, Al0, xf[0][0][0], xf[1][0][0], xf[2][0][0], acc0)
        MFMA_STEP(Ah1, Am1, Al1, xf[0][0][1], xf[1][0][1], xf[2][0][1], acc0)
        MFMA_STEP(Ah0, Am0, Al0, xf[0][1][0], xf[1][1][0], xf[2][1][0], acc1)
        MFMA_STEP(Ah1, Am1, Al1, xf[0][1][1], xf[1][1][1], xf[2][1][1], acc1)
#pragma unroll
        for (int r = 0; r < 4; ++r) {
            const int kk = ct * 16 + quad * 4 + r;
            float sc = hnA[r] - acc0[r];
            if (sc < v1[0]) { v2[0] = v1[0]; k2[0] = k1[0]; v1[0] = sc; k1[0] = kk; }
            else if (sc < v2[0]) { v2[0] = sc; k2[0] = kk; }
            sc = hnA[r] - acc1[r];
            if (sc < v1[1]) { v2[1] = v1[1]; k2[1] = k1[1]; v1[1] = sc; k1[1] = kk; }
            else if (sc < v2[1]) { v2[1] = sc; k2[1] = kk; }
        }

        // ---- prefetch tile ct+2 (A buffer, wraps harmlessly) under B compute ----
        const int offA = (((ct + 2) & 31)) * (16 * DDIM) + arow;
        Ah0 = *(const bf16x8*)(ebh + offA);
        Ah1 = *(const bf16x8*)(ebh + offA + 32);
        Am0 = *(const bf16x8*)(ebm + offA);
        Am1 = *(const bf16x8*)(ebm + offA + 32);
        Al0 = *(const bf16x8*)(ebl + offA);
        Al1 = *(const bf16x8*)(ebl + offA + 32);
        hnA = *(const f32x4*)(hnorms + ((ct + 2) & 31) * 16 + quad * 4);

        acc0 = (f32x4){0.f, 0.f, 0.f, 0.f};
        acc1 = (f32x4){0.f, 0.f, 0.f, 0.f};
        MFMA_STEP(Bh0, Bm0, Bl0, xf[0][0][0], xf[1][0][0], xf[2][0][0], acc0)
        MFMA_STEP(Bh1, Bm1, Bl1, xf[0][0][1], xf[1][0][1], xf[2][0][1], acc0)
        MFMA_STEP(Bh0, Bm0, Bl0, xf[0][1][0], xf[1][1][0], xf[2][1][0], acc1)
        MFMA_STEP(Bh1, Bm1, Bl1, xf[0][1][1], xf[1][1][1], xf[2][1][1], acc1)
#pragma unroll
        for (int r = 0; r < 4; ++r) {
            const int kk = (ct + 1) * 16 + quad * 4 + r;
            float sc = hnB[r] - acc0[r];
            if (sc < v1[0]) { v2[0] = v1[0]; k2[0] = k1[0]; v1[0] = sc; k1[0] = kk; }
            else if (sc < v2[0]) { v2[0] = sc; k2[0] = kk; }
            sc = hnB[r] - acc1[r];
            if (sc < v1[1]) { v2[1] = v1[1]; k2[1] = k1[1]; v1[1] = sc; k1[1] = kk; }
            else if (sc < v2[1]) { v2[1] = sc; k2[1] = kk; }
        }
    }

    // Cross-quad top-2 merge (lanes l, l^16, l^32 share pixel-col)
#pragma unroll
    for (int tt = 0; tt < 2; ++tt) {
#pragma unroll
        for (int off = 16; off <= 32; off <<= 1) {
            float w1 = __shfl_xor(v1[tt], off, 64); int j1 = __shfl_xor(k1[tt], off, 64);
            float w2 = __shfl_xor(v2[tt], off, 64); int j2 = __shfl_xor(k2[tt], off, 64);
            bool aF = (v1[tt] < w1) || (v1[tt] == w1 && k1[tt] < j1);
            float t1 = aF ? v1[tt] : w1;  int u1 = aF ? k1[tt] : j1;
            float tl = aF ? w1 : v1[tt];  int ul = aF ? j1 : k1[tt];      // loser of firsts
            bool bS = (v2[tt] < w2) || (v2[tt] == w2 && k2[tt] < j2);
            float tc = bS ? v2[tt] : w2;  int uc = bS ? k2[tt] : j2;      // better of seconds
            bool lS = (tl < tc) || (tl == tc && ul < uc);
            v1[tt] = t1; k1[tt] = u1;
            v2[tt] = lS ? tl : tc; k2[tt] = lS ? ul : uc;
        }
    }

    // Pixel q = lane&31; lanes l and l+32 handle the same pixel (tt = (l>>4)&1).
    const int q    = lane & 31;
    const int pp   = p0 + q;
    const int tsel = (lane >> 4) & 1;
    const int kA = tsel ? k1[1] : k1[0];
    const int kB = tsel ? k2[1] : k2[0];

    // Reload x (fp32, coalesced) for exact rescore + epilogue
    float x[DDIM];
#pragma unroll
    for (int c = 0; c < DDIM; ++c) x[c] = xb[c * HW + pp];

    // Exact fp32 rescore, split: lanes<32 score kA, lanes>=32 score kB.
    // Per-code chain byte-identical to the R5-passing kernel.
    const int kMine = (lane < 32) ? kA : kB;
    const float4* eM = (const float4*)(emb + kMine * DDIM);
    float a0 = hnorms[kMine], a1 = 0.f, a2 = 0.f, a3 = 0.f;
#pragma unroll
    for (int i = 0; i < 16; ++i) {
        float4 ea = eM[i];
        const int c = i * 4;
        a0 = fmaf(-x[c + 0], ea.x, a0);
        a1 = fmaf(-x[c + 1], ea.y, a1);
        a2 = fmaf(-x[c + 2], ea.z, a2);
        a3 = fmaf(-x[c + 3], ea.w, a3);
    }
    const float dMine = (a0 + a1) + (a2 + a3);
    const float dOth  = __shfl_xor(dMine, 32, 64);
    const float dA = (lane < 32) ? dMine : dOth;
    const float dB = (lane < 32) ? dOth  : dMine;
    const int myk = (dB < dA || (dB == dA && kB < kA)) ? kB : kA;

    float lsum = 0.f;
    if (lane < 32) {
        dout[IDX_OFF + b * HW + pp] = (float)myk;
        atomicAdd(&hist[myk], 1);
        const float4* qrow = (const float4*)(emb + myk * DDIM);
        float* ob = dout + OUT_OFF + b * BSTRIDE;
#pragma unroll
        for (int i = 0; i < 16; ++i) {
            float4 qv = qrow[i];
            const int c = i * 4;
            float d0 = qv.x - x[c + 0];
            float d1 = qv.y - x[c + 1];
            float d2 = qv.z - x[c + 2];
            float d3 = qv.w - x[c + 3];
            lsum += d0 * d0 + d1 * d1 + d2 * d2 + d3 * d3;
            ob[(c + 0) * HW + pp] = x[c + 0] + d0;   // reference rounding: x + (q - x)
            ob[(c + 1) * HW + pp] = x[c + 1] + d1;
            ob[(c + 2) * HW + pp] = x[c + 2] + d2;
            ob[(c + 3) * HW + pp] = x[c + 3] + d3;
        }
    }
    for (int off = 32; off > 0; off >>= 1) lsum += __shfl_down(lsum, off, 64);
    if (lane == 0) atomicAdd(loss_acc, lsum);

    __syncthreads();
    for (int k = t; k < KEMB; k += 256) {
        int v = hist[k];
        if (v) atomicAdd(&counts[k], v);
    }
}

__global__ void vq_fin(const int* __restrict__ counts,
                       const float* __restrict__ loss_acc,
                       float* __restrict__ dout) {
    __shared__ float red[KEMB];
    int k = threadIdx.x;            // 512 threads
    float c = (float)counts[k];
    float pa = c / (float)NPIX;
    red[k] = pa * logf(pa + 1e-10f);
    __syncthreads();
    for (int s = 256; s > 0; s >>= 1) {
        if (k < s) red[k] += red[k + s];
        __syncthreads();
    }
    if (k == 0) {
        dout[PERP_OFF] = expf(-red[0]);
        dout[0] = 0.25f * (*loss_acc) / 8388608.0f;
    }
}

extern "C" void kernel_launch(void* const* d_in, const int* in_sizes, int n_in,
                              void* d_out, int out_size, void* d_ws, size_t ws_size,
                              hipStream_t stream) {
    const float* in  = (const float*)d_in[0];   // 8388608 elems
    const float* emb = (const float*)d_in[1];   // 32768 elems
    float* dout = (float*)d_out;
    int*   counts   = (int*)d_ws;
    float* hnorms   = (float*)((char*)d_ws + 2048);
    float* loss_acc = (float*)((char*)d_ws + 4096);
    unsigned short* ebh = (unsigned short*)((char*)d_ws + 8192);
    unsigned short* ebm = ebh + KEMB * DDIM;
    unsigned short* ebl = ebm + KEMB * DDIM;

    vq_init<<<512, 64, 0, stream>>>(emb, counts, hnorms, loss_acc, ebh, ebm, ebl);
    vq_main<<<1024, 256, 0, stream>>>(in, emb, ebh, ebm, ebl, hnorms, counts, loss_acc, dout);
    vq_fin<<<1, 512, 0, stream>>>(counts, loss_acc, dout);
}

// Round 7
// 180.204 us; speedup vs baseline: 1.3170x; 1.3170x over previous
//
#include <hip/hip_runtime.h>
#include <math.h>

// Problem constants
#define NPIX   131072      // B*H*W = 32*64*64
#define KEMB   512
#define DDIM   64
#define HW     4096        // H*W
#define BSTRIDE 262144     // C*H*W

// d_out flat layout (float32): [loss(1) | out(8388608) | perplexity(1) | indices(131072)]
#define OUT_OFF  1
#define PERP_OFF 8388609
#define IDX_OFF  8388610

typedef __attribute__((ext_vector_type(8))) short bf16x8;   // 8 bf16 = 4 VGPRs (MFMA A/B frag)
typedef __attribute__((ext_vector_type(4))) float f32x4;    // MFMA C/D frag

__device__ __forceinline__ unsigned short bf16_rtne(float f) {
    unsigned int u = __float_as_uint(f);
    u += 0x7FFFu + ((u >> 16) & 1u);
    return (unsigned short)(u >> 16);
}
__device__ __forceinline__ float bf16_to_f(unsigned short h) {
    return __uint_as_float(((unsigned int)h) << 16);
}

// 6 split-products per k-step: hh, hm, mh, hl, lh, mm (R5 order — passed)
#define MFMA_STEP(AH, AM, AL, XH, XM, XL, ACC) \
    ACC = __builtin_amdgcn_mfma_f32_16x16x32_bf16(AH, XH, ACC, 0, 0, 0); \
    ACC = __builtin_amdgcn_mfma_f32_16x16x32_bf16(AH, XM, ACC, 0, 0, 0); \
    ACC = __builtin_amdgcn_mfma_f32_16x16x32_bf16(AM, XH, ACC, 0, 0, 0); \
    ACC = __builtin_amdgcn_mfma_f32_16x16x32_bf16(AH, XL, ACC, 0, 0, 0); \
    ACC = __builtin_amdgcn_mfma_f32_16x16x32_bf16(AL, XH, ACC, 0, 0, 0); \
    ACC = __builtin_amdgcn_mfma_f32_16x16x32_bf16(AM, XM, ACC, 0, 0, 0);

// ws layout: [0,2048) int counts | [2048,4096) float hnorms | [4096] loss |
//            [8192) ebh ushort[32768] | +64KB ebm | +64KB ebl
// R6-verbatim init (passed): 512 blocks x 64 threads, block = code, lane = channel.
__global__ void vq_init(const float* __restrict__ emb, int* __restrict__ counts,
                        float* __restrict__ hnorms, float* __restrict__ loss_acc,
                        unsigned short* __restrict__ ebh, unsigned short* __restrict__ ebm,
                        unsigned short* __restrict__ ebl) {
    const int k = blockIdx.x;
    const int c = threadIdx.x;
    float x = emb[k * DDIM + c];
    unsigned short h = bf16_rtne(x);
    float r1 = x - bf16_to_f(h);          // exact (Sterbenz)
    unsigned short m = bf16_rtne(r1);
    float r2 = r1 - bf16_to_f(m);         // exact
    unsigned short l = bf16_rtne(r2);
    ebh[k * DDIM + c] = h; ebm[k * DDIM + c] = m; ebl[k * DDIM + c] = l;
    float s = x * x;
#pragma unroll
    for (int off = 1; off <= 32; off <<= 1) s += __shfl_xor(s, off, 64);
    if (c == 0) {
        hnorms[k] = 0.5f * s;
        counts[k] = 0;
        if (k == 0) *loss_acc = 0.f;
    }
}

// Wave owns 64 pixels (4 B-tiles of N=16), block = 4 waves = 256 pixels.
// A-tiles staged to LDS in FRAGMENT ORDER (consumer ds_read_b128 at lane*16,
// conflict-free), double-buffered, shared by the 4 waves (4x L2-traffic cut,
// no global loads between barriers except the prefetch into registers).
__global__ __launch_bounds__(256, 2) void vq_main(
    const float* __restrict__ in, const float* __restrict__ emb,
    const unsigned short* __restrict__ ebh, const unsigned short* __restrict__ ebm,
    const unsigned short* __restrict__ ebl,
    const float* __restrict__ hnorms, int* __restrict__ counts,
    float* __restrict__ loss_acc, float* __restrict__ dout)
{
    __shared__ int hist[KEMB];                                  // 2 KB
    __shared__ __align__(16) float hn_lds[KEMB];                // 2 KB
    __shared__ __align__(16) unsigned short atile[2][3072];     // 12 KB dbuf

    const int t = threadIdx.x;
    hist[t] = 0; hist[t + 256] = 0;
    if (t < 128) ((float4*)hn_lds)[t] = ((const float4*)hnorms)[t];

    const int lane = t & 63;
    const int wid  = t >> 6;
    const int quad = lane >> 4;
    const int col  = lane & 15;
    const int b    = blockIdx.x >> 4;
    const int p0   = ((blockIdx.x & 15) << 8) | (wid << 6);   // first of 64 pixels
    const float* xb = in + b * BSTRIDE;

    // Staging assignment: fragment f1 = t (splits 0,1), f2 = t+256 (split 2, t<128).
    // Fragment (split, kstep, lf): src = tab[split] + ct*1024 + (lf&15)*64 + kstep*32 + (lf>>4)*8
    //                              dst = atile[buf] + split*1024 + kstep*512 + lf*8
    const int s1  = t >> 7;              // 0 (waves 0,1) or 1 (waves 2,3)
    const int ks  = (t >> 6) & 1;        // kstep, same for f1 and f2
    const int lf  = t & 63;
    const unsigned short* tab1 = s1 ? ebm : ebh;
    const int src_off = (lf & 15) * 64 + ks * 32 + (lf >> 4) * 8;
    const int dst1 = s1 * 1024 + ks * 512 + lf * 8;
    const int dst2 = 2 * 1024 + ks * 512 + lf * 8;

    // ---- Build x B-fragments: B[n=col][k=quad*8+j], xf[split][ptile][kstep] ----
    bf16x8 xf[3][4][2];
#pragma unroll
    for (int tt = 0; tt < 4; ++tt) {
#pragma unroll
        for (int s = 0; s < 2; ++s) {
            const int pp = p0 + tt * 16 + col;
            const int c0 = s * 32 + quad * 8;
            bf16x8 vh, vm, vl;
#pragma unroll
            for (int j = 0; j < 8; ++j) {
                float x = xb[(c0 + j) * HW + pp];
                unsigned short h = bf16_rtne(x);
                float r1 = x - bf16_to_f(h);
                unsigned short m = bf16_rtne(r1);
                float r2 = r1 - bf16_to_f(m);
                unsigned short l = bf16_rtne(r2);
                vh[j] = (short)h; vm[j] = (short)m; vl[j] = (short)l;
            }
            xf[0][tt][s] = vh; xf[1][tt][s] = vm; xf[2][tt][s] = vl;
        }
    }

    // Stage tile 0 into buffer 0
    *(bf16x8*)&atile[0][dst1] = *(const bf16x8*)(tab1 + src_off);
    if (t < 128) *(bf16x8*)&atile[0][dst2] = *(const bf16x8*)(ebl + src_off);
    __syncthreads();

    // top-2 tracking per pixel-tile (lex order on (value, index)) — R5 verbatim
    float v1[4], v2[4]; int k1[4], k2[4];
#pragma unroll
    for (int tt = 0; tt < 4; ++tt) {
        v1[tt] = 3.402823466e38f; v2[tt] = 3.402823466e38f; k1[tt] = 0; k2[tt] = 0;
    }

    for (int ct = 0; ct < 32; ++ct) {
        const int cur = ct & 1;
        // Prefetch tile ct+1 fragments into registers (drains under the MFMA block)
        bf16x8 g1, g2;
        if (ct < 31) {
            const int sb = (ct + 1) * 1024 + src_off;
            g1 = *(const bf16x8*)(tab1 + sb);
            if (t < 128) g2 = *(const bf16x8*)(ebl + sb);
        }

        // LDS -> A fragments (conflict-free b128 at lane*16)
        const unsigned short* abuf = atile[cur];
        const bf16x8 Ah0 = *(const bf16x8*)&abuf[           lane * 8];
        const bf16x8 Ah1 = *(const bf16x8*)&abuf[ 512 +     lane * 8];
        const bf16x8 Am0 = *(const bf16x8*)&abuf[1024 +     lane * 8];
        const bf16x8 Am1 = *(const bf16x8*)&abuf[1536 +     lane * 8];
        const bf16x8 Al0 = *(const bf16x8*)&abuf[2048 +     lane * 8];
        const bf16x8 Al1 = *(const bf16x8*)&abuf[2560 +     lane * 8];

        f32x4 acc[4];
#pragma unroll
        for (int tt = 0; tt < 4; ++tt) acc[tt] = (f32x4){0.f, 0.f, 0.f, 0.f};
#pragma unroll
        for (int tt = 0; tt < 4; ++tt) {
            MFMA_STEP(Ah0, Am0, Al0, xf[0][tt][0], xf[1][tt][0], xf[2][tt][0], acc[tt])
            MFMA_STEP(Ah1, Am1, Al1, xf[0][tt][1], xf[1][tt][1], xf[2][tt][1], acc[tt])
        }

        const f32x4 hn = *(const f32x4*)&hn_lds[ct * 16 + quad * 4];
#pragma unroll
        for (int tt = 0; tt < 4; ++tt) {
#pragma unroll
            for (int r = 0; r < 4; ++r) {
                const float sc = hn[r] - acc[tt][r];
                const int   kk = ct * 16 + quad * 4 + r;
                if (sc < v1[tt]) { v2[tt] = v1[tt]; k2[tt] = k1[tt]; v1[tt] = sc; k1[tt] = kk; }
                else if (sc < v2[tt]) { v2[tt] = sc; k2[tt] = kk; }
            }
        }

        // Write prefetched fragments into the other buffer, then one barrier
        if (ct < 31) {
            const int nxt = cur ^ 1;
            *(bf16x8*)&atile[nxt][dst1] = g1;
            if (t < 128) *(bf16x8*)&atile[nxt][dst2] = g2;
        }
        __syncthreads();
    }

    // Cross-quad top-2 merge (lanes l, l^16, l^32 share pixel-col) — R5 verbatim
#pragma unroll
    for (int tt = 0; tt < 4; ++tt) {
#pragma unroll
        for (int off = 16; off <= 32; off <<= 1) {
            float w1 = __shfl_xor(v1[tt], off, 64); int j1 = __shfl_xor(k1[tt], off, 64);
            float w2 = __shfl_xor(v2[tt], off, 64); int j2 = __shfl_xor(k2[tt], off, 64);
            bool aF = (v1[tt] < w1) || (v1[tt] == w1 && k1[tt] < j1);
            float t1 = aF ? v1[tt] : w1;  int u1 = aF ? k1[tt] : j1;
            float tl = aF ? w1 : v1[tt];  int ul = aF ? j1 : k1[tt];      // loser of firsts
            bool bS = (v2[tt] < w2) || (v2[tt] == w2 && k2[tt] < j2);
            float tc = bS ? v2[tt] : w2;  int uc = bS ? k2[tt] : j2;      // better of seconds
            bool lS = (tl < tc) || (tl == tc && ul < uc);
            v1[tt] = t1; k1[tt] = u1;
            v2[tt] = lS ? tl : tc; k2[tt] = lS ? ul : uc;
        }
    }
    const int kA = k1[quad], kB = k2[quad];   // lane's own pixel = p0 + lane
    const int pp = p0 + lane;

    // Reload x (fp32, coalesced) for exact rescore + epilogue — R5 verbatim
    float x[DDIM];
#pragma unroll
    for (int c = 0; c < DDIM; ++c) x[c] = xb[c * HW + pp];

    // Exact fp32 rescore (dual chains, bitwise == R5/R6 chains)
    const float4* eA = (const float4*)(emb + kA * DDIM);
    const float4* eB = (const float4*)(emb + kB * DDIM);
    float a0 = hn_lds[kA], a1 = 0.f, a2 = 0.f, a3 = 0.f;
    float b0 = hn_lds[kB], b1 = 0.f, b2 = 0.f, b3 = 0.f;
#pragma unroll
    for (int i = 0; i < 16; ++i) {
        float4 ea = eA[i], eb = eB[i];
        const int c = i * 4;
        a0 = fmaf(-x[c + 0], ea.x, a0);
        a1 = fmaf(-x[c + 1], ea.y, a1);
        a2 = fmaf(-x[c + 2], ea.z, a2);
        a3 = fmaf(-x[c + 3], ea.w, a3);
        b0 = fmaf(-x[c + 0], eb.x, b0);
        b1 = fmaf(-x[c + 1], eb.y, b1);
        b2 = fmaf(-x[c + 2], eb.z, b2);
        b3 = fmaf(-x[c + 3], eb.w, b3);
    }
    const float dA = (a0 + a1) + (a2 + a3);
    const float dB = (b0 + b1) + (b2 + b3);
    const int myk = (dB < dA || (dB == dA && kB < kA)) ? kB : kA;

    dout[IDX_OFF + b * HW + pp] = (float)myk;
    atomicAdd(&hist[myk], 1);

    // Epilogue: gather chosen code, ST output + loss (reference rounding x+(q-x))
    const float4* qrow = (const float4*)(emb + myk * DDIM);
    float* ob = dout + OUT_OFF + b * BSTRIDE;
    float lsum = 0.f;
#pragma unroll
    for (int i = 0; i < 16; ++i) {
        float4 qv = qrow[i];
        const int c = i * 4;
        float d0 = qv.x - x[c + 0];
        float d1 = qv.y - x[c + 1];
        float d2 = qv.z - x[c + 2];
        float d3 = qv.w - x[c + 3];
        lsum += d0 * d0 + d1 * d1 + d2 * d2 + d3 * d3;
        ob[(c + 0) * HW + pp] = x[c + 0] + d0;
        ob[(c + 1) * HW + pp] = x[c + 1] + d1;
        ob[(c + 2) * HW + pp] = x[c + 2] + d2;
        ob[(c + 3) * HW + pp] = x[c + 3] + d3;
    }
    for (int off = 32; off > 0; off >>= 1) lsum += __shfl_down(lsum, off, 64);
    if (lane == 0) atomicAdd(loss_acc, lsum);

    __syncthreads();
    for (int k = t; k < KEMB; k += 256) {
        int v = hist[k];
        if (v) atomicAdd(&counts[k], v);
    }
}

__global__ void vq_fin(const int* __restrict__ counts,
                       const float* __restrict__ loss_acc,
                       float* __restrict__ dout) {
    __shared__ float red[KEMB];
    int k = threadIdx.x;            // 512 threads
    float c = (float)counts[k];
    float pa = c / (float)NPIX;
    red[k] = pa * logf(pa + 1e-10f);
    __syncthreads();
    for (int s = 256; s > 0; s >>= 1) {
        if (k < s) red[k] += red[k + s];
        __syncthreads();
    }
    if (k == 0) {
        dout[PERP_OFF] = expf(-red[0]);
        dout[0] = 0.25f * (*loss_acc) / 8388608.0f;
    }
}

extern "C" void kernel_launch(void* const* d_in, const int* in_sizes, int n_in,
                              void* d_out, int out_size, void* d_ws, size_t ws_size,
                              hipStream_t stream) {
    const float* in  = (const float*)d_in[0];   // 8388608 elems
    const float* emb = (const float*)d_in[1];   // 32768 elems
    float* dout = (float*)d_out;
    int*   counts   = (int*)d_ws;
    float* hnorms   = (float*)((char*)d_ws + 2048);
    float* loss_acc = (float*)((char*)d_ws + 4096);
    unsigned short* ebh = (unsigned short*)((char*)d_ws + 8192);
    unsigned short* ebm = ebh + KEMB * DDIM;
    unsigned short* ebl = ebm + KEMB * DDIM;

    vq_init<<<512, 64, 0, stream>>>(emb, counts, hnorms, loss_acc, ebh, ebm, ebl);
    vq_main<<<512, 256, 0, stream>>>(in, emb, ebh, ebm, ebl, hnorms, counts, loss_acc, dout);
    vq_fin<<<1, 512, 0, stream>>>(counts, loss_acc, dout);
}

// Round 9
// 178.632 us; speedup vs baseline: 1.3286x; 1.0088x over previous
//
#include <hip/hip_runtime.h>
#include <math.h>

// Problem constants
#define NPIX   131072      // B*H*W = 32*64*64
#define KEMB   512
#define DDIM   64
#define HW     4096        // H*W
#define BSTRIDE 262144     // C*H*W

// d_out flat layout (float32): [loss(1) | out(8388608) | perplexity(1) | indices(131072)]
#define OUT_OFF  1
#define PERP_OFF 8388609
#define IDX_OFF  8388610

typedef __attribute__((ext_vector_type(8))) short bf16x8;   // 8 bf16 = 4 VGPRs (MFMA A/B frag)
typedef __attribute__((ext_vector_type(4))) float f32x4;    // MFMA C/D frag

__device__ __forceinline__ unsigned short bf16_rtne(float f) {
    unsigned int u = __float_as_uint(f);
    u += 0x7FFFu + ((u >> 16) & 1u);
    return (unsigned short)(u >> 16);
}
__device__ __forceinline__ float bf16_to_f(unsigned short h) {
    return __uint_as_float(((unsigned int)h) << 16);
}

// 6 split-products per k-step: hh, hm, mh, hl, lh, mm (R5/R7 order — passed)
#define MFMA_STEP(AH, AM, AL, XH, XM, XL, ACC) \
    ACC = __builtin_amdgcn_mfma_f32_16x16x32_bf16(AH, XH, ACC, 0, 0, 0); \
    ACC = __builtin_amdgcn_mfma_f32_16x16x32_bf16(AH, XM, ACC, 0, 0, 0); \
    ACC = __builtin_amdgcn_mfma_f32_16x16x32_bf16(AM, XH, ACC, 0, 0, 0); \
    ACC = __builtin_amdgcn_mfma_f32_16x16x32_bf16(AH, XL, ACC, 0, 0, 0); \
    ACC = __builtin_amdgcn_mfma_f32_16x16x32_bf16(AL, XH, ACC, 0, 0, 0); \
    ACC = __builtin_amdgcn_mfma_f32_16x16x32_bf16(AM, XM, ACC, 0, 0, 0);

// One 16-code tile: LDS frag reads + 8x MFMA_STEP + top-2 update. R7-verbatim
// numerics (per-tile accumulation order and argmin update order unchanged).
#define TILE_COMPUTE(ABUF, KBASE) { \
    const unsigned short* abuf_ = (ABUF); \
    const bf16x8 Ah0 = *(const bf16x8*)&abuf_[          lane * 8]; \
    const bf16x8 Ah1 = *(const bf16x8*)&abuf_[ 512 +    lane * 8]; \
    const bf16x8 Am0 = *(const bf16x8*)&abuf_[1024 +    lane * 8]; \
    const bf16x8 Am1 = *(const bf16x8*)&abuf_[1536 +    lane * 8]; \
    const bf16x8 Al0 = *(const bf16x8*)&abuf_[2048 +    lane * 8]; \
    const bf16x8 Al1 = *(const bf16x8*)&abuf_[2560 +    lane * 8]; \
    f32x4 acc[4]; \
    _Pragma("unroll") \
    for (int tt = 0; tt < 4; ++tt) acc[tt] = (f32x4){0.f, 0.f, 0.f, 0.f}; \
    _Pragma("unroll") \
    for (int tt = 0; tt < 4; ++tt) { \
        MFMA_STEP(Ah0, Am0, Al0, xf[0][tt][0], xf[1][tt][0], xf[2][tt][0], acc[tt]) \
        MFMA_STEP(Ah1, Am1, Al1, xf[0][tt][1], xf[1][tt][1], xf[2][tt][1], acc[tt]) \
    } \
    const f32x4 hn = *(const f32x4*)&hn_lds[(KBASE) + quad * 4]; \
    _Pragma("unroll") \
    for (int tt = 0; tt < 4; ++tt) { \
        _Pragma("unroll") \
        for (int r = 0; r < 4; ++r) { \
            const float sc = hn[r] - acc[tt][r]; \
            const int   kk = (KBASE) + quad * 4 + r; \
            if (sc < v1[tt]) { v2[tt] = v1[tt]; k2[tt] = k1[tt]; v1[tt] = sc; k1[tt] = kk; } \
            else if (sc < v2[tt]) { v2[tt] = sc; k2[tt] = kk; } \
        } \
    } \
}

// ws layout: [0,2048) int counts | [2048,4096) float hnorms | [4096] loss |
//            [8192) ebh ushort[32768] | +64KB ebm | +64KB ebl
// R6/R7-verbatim init (passed): 512 blocks x 64 threads, block=code, lane=channel.
__global__ void vq_init(const float* __restrict__ emb, int* __restrict__ counts,
                        float* __restrict__ hnorms, float* __restrict__ loss_acc,
                        unsigned short* __restrict__ ebh, unsigned short* __restrict__ ebm,
                        unsigned short* __restrict__ ebl) {
    const int k = blockIdx.x;
    const int c = threadIdx.x;
    float x = emb[k * DDIM + c];
    unsigned short h = bf16_rtne(x);
    float r1 = x - bf16_to_f(h);          // exact (Sterbenz)
    unsigned short m = bf16_rtne(r1);
    float r2 = r1 - bf16_to_f(m);         // exact
    unsigned short l = bf16_rtne(r2);
    ebh[k * DDIM + c] = h; ebm[k * DDIM + c] = m; ebl[k * DDIM + c] = l;
    float s = x * x;
#pragma unroll
    for (int off = 1; off <= 32; off <<= 1) s += __shfl_xor(s, off, 64);
    if (c == 0) {
        hnorms[k] = 0.5f * s;
        counts[k] = 0;
        if (k == 0) *loss_acc = 0.f;
    }
}

// Wave owns 64 pixels (4 B-tiles of N=16), block = 4 waves = 256 pixels.
// TWO 16-code tiles per LDS buffer / barrier phase (16 phases of 96 MFMAs,
// vs R7's 32 phases of 48) — halves barrier drains, doubles latency hiding.
// All fragment/staging indices static; double-buffer alternation positional.
__global__ __launch_bounds__(256, 2) void vq_main(
    const float* __restrict__ in, const float* __restrict__ emb,
    const unsigned short* __restrict__ ebh, const unsigned short* __restrict__ ebm,
    const unsigned short* __restrict__ ebl,
    const float* __restrict__ hnorms, int* __restrict__ counts,
    float* __restrict__ loss_acc, float* __restrict__ dout)
{
    __shared__ int hist[KEMB];                                  // 2 KB
    __shared__ __align__(16) float hn_lds[KEMB];                // 2 KB
    __shared__ __align__(16) unsigned short atile[2][2][3072];  // 24 KB dbuf (2 tiles/buf)

    const int t = threadIdx.x;
    hist[t] = 0; hist[t + 256] = 0;
    if (t < 128) ((float4*)hn_lds)[t] = ((const float4*)hnorms)[t];

    const int lane = t & 63;
    const int wid  = t >> 6;
    const int quad = lane >> 4;
    const int col  = lane & 15;
    const int b    = blockIdx.x >> 4;
    const int p0   = ((blockIdx.x & 15) << 8) | (wid << 6);   // first of 64 pixels
    const float* xb = in + b * BSTRIDE;

    // Staging assignment (R7-verbatim mapping): f1 = t (splits 0,1), f2 (split 2, t<128)
    const int s1  = t >> 7;
    const int ks  = (t >> 6) & 1;
    const int lf  = t & 63;
    const unsigned short* tab1 = s1 ? ebm : ebh;
    const int src_off = (lf & 15) * 64 + ks * 32 + (lf >> 4) * 8;
    const int dst1 = s1 * 1024 + ks * 512 + lf * 8;
    const int dst2 = 2 * 1024 + ks * 512 + lf * 8;

    // ---- Build x B-fragments: B[n=col][k=quad*8+j], xf[split][ptile][kstep] ----
    bf16x8 xf[3][4][2];
#pragma unroll
    for (int tt = 0; tt < 4; ++tt) {
#pragma unroll
        for (int s = 0; s < 2; ++s) {
            const int pp = p0 + tt * 16 + col;
            const int c0 = s * 32 + quad * 8;
            bf16x8 vh, vm, vl;
#pragma unroll
            for (int j = 0; j < 8; ++j) {
                float x = xb[(c0 + j) * HW + pp];
                unsigned short h = bf16_rtne(x);
                float r1 = x - bf16_to_f(h);
                unsigned short m = bf16_rtne(r1);
                float r2 = r1 - bf16_to_f(m);
                unsigned short l = bf16_rtne(r2);
                vh[j] = (short)h; vm[j] = (short)m; vl[j] = (short)l;
            }
            xf[0][tt][s] = vh; xf[1][tt][s] = vm; xf[2][tt][s] = vl;
        }
    }

    // Stage tiles 0,1 into buffer 0
    *(bf16x8*)&atile[0][0][dst1] = *(const bf16x8*)(tab1 + src_off);
    *(bf16x8*)&atile[0][1][dst1] = *(const bf16x8*)(tab1 + 1024 + src_off);
    if (t < 128) {
        *(bf16x8*)&atile[0][0][dst2] = *(const bf16x8*)(ebl + src_off);
        *(bf16x8*)&atile[0][1][dst2] = *(const bf16x8*)(ebl + 1024 + src_off);
    }
    __syncthreads();

    // top-2 tracking per pixel-tile (lex order on (value, index)) — R7 verbatim
    float v1[4], v2[4]; int k1[4], k2[4];
#pragma unroll
    for (int tt = 0; tt < 4; ++tt) {
        v1[tt] = 3.402823466e38f; v2[tt] = 3.402823466e38f; k1[tt] = 0; k2[tt] = 0;
    }

    for (int ph = 0; ph < 16; ++ph) {
        const int cur = ph & 1;
        // Prefetch the next tile pair into registers (drains under 96 MFMAs)
        bf16x8 g1a, g1b, g2a, g2b;
        if (ph < 15) {
            const int sbA = (2 * ph + 2) * 1024 + src_off;
            const int sbB = (2 * ph + 3) * 1024 + src_off;
            g1a = *(const bf16x8*)(tab1 + sbA);
            g1b = *(const bf16x8*)(tab1 + sbB);
            if (t < 128) {
                g2a = *(const bf16x8*)(ebl + sbA);
                g2b = *(const bf16x8*)(ebl + sbB);
            }
        }

        TILE_COMPUTE(atile[cur][0], (2 * ph) * 16)
        TILE_COMPUTE(atile[cur][1], (2 * ph + 1) * 16)

        // Write prefetched pair into the other buffer, then one barrier
        if (ph < 15) {
            const int nxt = cur ^ 1;
            *(bf16x8*)&atile[nxt][0][dst1] = g1a;
            *(bf16x8*)&atile[nxt][1][dst1] = g1b;
            if (t < 128) {
                *(bf16x8*)&atile[nxt][0][dst2] = g2a;
                *(bf16x8*)&atile[nxt][1][dst2] = g2b;
            }
        }
        __syncthreads();
    }

    // Cross-quad top-2 merge (lanes l, l^16, l^32 share pixel-col) — R7 verbatim
#pragma unroll
    for (int tt = 0; tt < 4; ++tt) {
#pragma unroll
        for (int off = 16; off <= 32; off <<= 1) {
            float w1 = __shfl_xor(v1[tt], off, 64); int j1 = __shfl_xor(k1[tt], off, 64);
            float w2 = __shfl_xor(v2[tt], off, 64); int j2 = __shfl_xor(k2[tt], off, 64);
            bool aF = (v1[tt] < w1) || (v1[tt] == w1 && k1[tt] < j1);
            float t1 = aF ? v1[tt] : w1;  int u1 = aF ? k1[tt] : j1;
            float tl = aF ? w1 : v1[tt];  int ul = aF ? j1 : k1[tt];      // loser of firsts
            bool bS = (v2[tt] < w2) || (v2[tt] == w2 && k2[tt] < j2);
            float tc = bS ? v2[tt] : w2;  int uc = bS ? k2[tt] : j2;      // better of seconds
            bool lS = (tl < tc) || (tl == tc && ul < uc);
            v1[tt] = t1; k1[tt] = u1;
            v2[tt] = lS ? tl : tc; k2[tt] = lS ? ul : uc;
        }
    }
    const int kA = k1[quad], kB = k2[quad];   // lane's own pixel = p0 + lane
    const int pp = p0 + lane;

    // Reload x (fp32, coalesced) for exact rescore + epilogue — R7 verbatim
    float x[DDIM];
#pragma unroll
    for (int c = 0; c < DDIM; ++c) x[c] = xb[c * HW + pp];

    // Exact fp32 rescore (dual chains, bitwise == R5/R7 chains)
    const float4* eA = (const float4*)(emb + kA * DDIM);
    const float4* eB = (const float4*)(emb + kB * DDIM);
    float a0 = hn_lds[kA], a1 = 0.f, a2 = 0.f, a3 = 0.f;
    float b0 = hn_lds[kB], b1 = 0.f, b2 = 0.f, b3 = 0.f;
#pragma unroll
    for (int i = 0; i < 16; ++i) {
        float4 ea = eA[i], eb = eB[i];
        const int c = i * 4;
        a0 = fmaf(-x[c + 0], ea.x, a0);
        a1 = fmaf(-x[c + 1], ea.y, a1);
        a2 = fmaf(-x[c + 2], ea.z, a2);
        a3 = fmaf(-x[c + 3], ea.w, a3);
        b0 = fmaf(-x[c + 0], eb.x, b0);
        b1 = fmaf(-x[c + 1], eb.y, b1);
        b2 = fmaf(-x[c + 2], eb.z, b2);
        b3 = fmaf(-x[c + 3], eb.w, b3);
    }
    const float dA = (a0 + a1) + (a2 + a3);
    const float dB = (b0 + b1) + (b2 + b3);
    const int myk = (dB < dA || (dB == dA && kB < kA)) ? kB : kA;

    dout[IDX_OFF + b * HW + pp] = (float)myk;
    atomicAdd(&hist[myk], 1);

    // Epilogue: gather chosen code, ST output + loss (reference rounding x+(q-x))
    const float4* qrow = (const float4*)(emb + myk * DDIM);
    float* ob = dout + OUT_OFF + b * BSTRIDE;
    float lsum = 0.f;
#pragma unroll
    for (int i = 0; i < 16; ++i) {
        float4 qv = qrow[i];
        const int c = i * 4;
        float d0 = qv.x - x[c + 0];
        float d1 = qv.y - x[c + 1];
        float d2 = qv.z - x[c + 2];
        float d3 = qv.w - x[c + 3];
        lsum += d0 * d0 + d1 * d1 + d2 * d2 + d3 * d3;
        ob[(c + 0) * HW + pp] = x[c + 0] + d0;
        ob[(c + 1) * HW + pp] = x[c + 1] + d1;
        ob[(c + 2) * HW + pp] = x[c + 2] + d2;
        ob[(c + 3) * HW + pp] = x[c + 3] + d3;
    }
    for (int off = 32; off > 0; off >>= 1) lsum += __shfl_down(lsum, off, 64);
    if (lane == 0) atomicAdd(loss_acc, lsum);

    __syncthreads();
    for (int k = t; k < KEMB; k += 256) {
        int v = hist[k];
        if (v) atomicAdd(&counts[k], v);
    }
}

__global__ void vq_fin(const int* __restrict__ counts,
                       const float* __restrict__ loss_acc,
                       float* __restrict__ dout) {
    __shared__ float part[8];
    const int k = threadIdx.x;            // 512 threads = 8 waves
    float pa = (float)counts[k] / (float)NPIX;
    float v = pa * logf(pa + 1e-10f);
#pragma unroll
    for (int off = 1; off <= 32; off <<= 1) v += __shfl_xor(v, off, 64);
    if ((k & 63) == 0) part[k >> 6] = v;
    __syncthreads();
    if (k == 0) {
        float s = 0.f;
#pragma unroll
        for (int i = 0; i < 8; ++i) s += part[i];
        dout[PERP_OFF] = expf(-s);
        dout[0] = 0.25f * (*loss_acc) / 8388608.0f;
    }
}

extern "C" void kernel_launch(void* const* d_in, const int* in_sizes, int n_in,
                              void* d_out, int out_size, void* d_ws, size_t ws_size,
                              hipStream_t stream) {
    const float* in  = (const float*)d_in[0];   // 8388608 elems
    const float* emb = (const float*)d_in[1];   // 32768 elems
    float* dout = (float*)d_out;
    int*   counts   = (int*)d_ws;
    float* hnorms   = (float*)((char*)d_ws + 2048);
    float* loss_acc = (float*)((char*)d_ws + 4096);
    unsigned short* ebh = (unsigned short*)((char*)d_ws + 8192);
    unsigned short* ebm = ebh + KEMB * DDIM;
    unsigned short* ebl = ebm + KEMB * DDIM;

    vq_init<<<512, 64, 0, stream>>>(emb, counts, hnorms, loss_acc, ebh, ebm, ebl);
    vq_main<<<512, 256, 0, stream>>>(in, emb, ebh, ebm, ebl, hnorms, counts, loss_acc, dout);
    vq_fin<<<1, 512, 0, stream>>>(counts, loss_acc, dout);
}